// Round 1
// baseline (337.519 us; speedup 1.0000x reference)
//
#include <hip/hip_runtime.h>
#include <math.h>

// Problem constants: B=64, N=27, D=512. EPS=1e-5.
// Key identity: both cross-attentions have K/V constant along the key axis
// -> softmax exactly uniform -> output == the (identical) V row. All N^2
// tensors are broadcasts of per-batch (B,D) vectors; msg BN stats decompose.

#define EPSC 1e-5f

// ---------- 1. gf[b,d] = mean_n x[b,n,d] ----------
__global__ __launch_bounds__(256) void colmean_k(const float* __restrict__ x, float* __restrict__ gf) {
    int q = blockIdx.x * 256 + threadIdx.x;   // 0..32767
    int b = q >> 9, d = q & 511;
    const float* p = x + (size_t)b * 13824 + d;
    float s = 0.f;
#pragma unroll
    for (int n = 0; n < 27; n++) s += p[n << 9];
    gf[q] = s * (1.0f / 27.0f);
}

// ---------- small GEMM: Y[b,d] = sum_k X[b,k] * W[d,k] (+bias), B=64,D=K=512 ----------
__global__ __launch_bounds__(256) void small_gemm_k(const float* __restrict__ X, const float* __restrict__ W,
                                                    const float* __restrict__ bias, float* __restrict__ Y) {
    __shared__ float xs[512];
    int t = threadIdx.x;
    int b = blockIdx.x >> 1;
    int d = ((blockIdx.x & 1) << 8) + t;
    xs[t] = X[(b << 9) + t];
    xs[t + 256] = X[(b << 9) + t + 256];
    __syncthreads();
    const float4* wr = (const float4*)(W + (size_t)d * 512);
    const float4* xr = (const float4*)xs;
    float a0 = 0, a1 = 0, a2 = 0, a3 = 0;
#pragma unroll 8
    for (int k = 0; k < 128; k++) {
        float4 xv = xr[k]; float4 wv = wr[k];
        a0 = fmaf(xv.x, wv.x, a0); a1 = fmaf(xv.y, wv.y, a1);
        a2 = fmaf(xv.z, wv.z, a2); a3 = fmaf(xv.w, wv.w, a3);
    }
    float r = (a0 + a1) + (a2 + a3);
    if (bias) r += bias[d];
    Y[(b << 9) + d] = r;
}

// ---------- BN over batch (per-d over 64 b) + ReLU ----------
__global__ __launch_bounds__(256) void bn_batch_relu_k(const float* __restrict__ g0, float* __restrict__ g) {
    int d = blockIdx.x * 256 + threadIdx.x;   // grid 2 -> 0..511
    float s = 0, s2 = 0;
    for (int b = 0; b < 64; b++) { float v = g0[(b << 9) + d]; s += v; s2 = fmaf(v, v, s2); }
    float m = s * (1.f / 64.f);
    float var = s2 * (1.f / 64.f) - m * m;
    float rs = 1.f / sqrtf(var + EPSC);
    for (int b = 0; b < 64; b++) {
        float v = (g0[(b << 9) + d] - m) * rs;
        g[(b << 9) + d] = fmaxf(v, 0.f);
    }
}

// ---------- scalar BN over all (b,d) of e0 -> eN ----------
__global__ __launch_bounds__(1024) void scalar_bn_k(const float* __restrict__ e0, float* __restrict__ eN) {
    int t = threadIdx.x;
    float s = 0, s2 = 0;
    for (int q = t; q < 32768; q += 1024) { float v = e0[q]; s += v; s2 = fmaf(v, v, s2); }
    for (int off = 32; off > 0; off >>= 1) { s += __shfl_down(s, off); s2 += __shfl_down(s2, off); }
    __shared__ float p1[16], p2[16];
    __shared__ float mb[2];
    int wid = t >> 6, lane = t & 63;
    if (lane == 0) { p1[wid] = s; p2[wid] = s2; }
    __syncthreads();
    if (t == 0) {
        float S = 0, S2 = 0;
        for (int w = 0; w < 16; w++) { S += p1[w]; S2 += p2[w]; }
        float m = S * (1.f / 32768.f);
        float var = S2 * (1.f / 32768.f) - m * m;
        mb[0] = m; mb[1] = 1.f / sqrtf(var + EPSC);
    }
    __syncthreads();
    float m = mb[0], rs = mb[1];
    for (int q = t; q < 32768; q += 1024) eN[q] = (e0[q] - m) * rs;
}

// ---------- 4-way tiled fp32 GEMM: Y[r,d] = sum_k X[r,k] W[d,k]; M=1728,N=512,K=512 ----------
__global__ __launch_bounds__(256) void gemm4_k(const float* __restrict__ X,
        const float* __restrict__ W0, const float* __restrict__ W1,
        const float* __restrict__ W2, const float* __restrict__ W3,
        float* __restrict__ Y0, float* __restrict__ Y1,
        float* __restrict__ Y2, float* __restrict__ Y3) {
    __shared__ float Xs[16][68];
    __shared__ float Ws[16][68];
    const float* W; float* Y;
    switch (blockIdx.z) {
        case 0:  W = W0; Y = Y0; break;
        case 1:  W = W1; Y = Y1; break;
        case 2:  W = W2; Y = Y2; break;
        default: W = W3; Y = Y3; break;
    }
    int t = threadIdx.x;
    int r0 = blockIdx.x * 64;
    int d0 = blockIdx.y * 64;
    int lrow = t >> 2;
    int lk4 = (t & 3) * 4;
    int tm = (t >> 4) * 4;
    int tn = (t & 15) * 4;
    float acc[4][4] = {};
    for (int k0 = 0; k0 < 512; k0 += 16) {
        float4 xv = *(const float4*)(X + (size_t)(r0 + lrow) * 512 + k0 + lk4);
        float4 wv = *(const float4*)(W + (size_t)(d0 + lrow) * 512 + k0 + lk4);
        Xs[lk4 + 0][lrow] = xv.x; Xs[lk4 + 1][lrow] = xv.y;
        Xs[lk4 + 2][lrow] = xv.z; Xs[lk4 + 3][lrow] = xv.w;
        Ws[lk4 + 0][lrow] = wv.x; Ws[lk4 + 1][lrow] = wv.y;
        Ws[lk4 + 2][lrow] = wv.z; Ws[lk4 + 3][lrow] = wv.w;
        __syncthreads();
#pragma unroll
        for (int kk = 0; kk < 16; kk++) {
            float4 xa = *(const float4*)&Xs[kk][tm];
            float4 wb = *(const float4*)&Ws[kk][tn];
            float xr[4] = {xa.x, xa.y, xa.z, xa.w};
            float wr[4] = {wb.x, wb.y, wb.z, wb.w};
#pragma unroll
            for (int ii = 0; ii < 4; ii++)
#pragma unroll
                for (int jj = 0; jj < 4; jj++)
                    acc[ii][jj] = fmaf(xr[ii], wr[jj], acc[ii][jj]);
        }
        __syncthreads();
    }
    for (int ii = 0; ii < 4; ii++) {
        float4 o = {acc[ii][0], acc[ii][1], acc[ii][2], acc[ii][3]};
        *(float4*)(Y + (size_t)(r0 + tm + ii) * 512 + d0 + tn) = o;
    }
}

// ---------- per-i sums over (b,d): S, S^2, S*eE -> o[i], o[27+i], o[54+i] ----------
__global__ __launch_bounds__(256) void row_sums_k(const float* __restrict__ A, const float* __restrict__ eE,
                                                  float* __restrict__ o) {
    int i = blockIdx.x, t = threadIdx.x;
    float s = 0, s2 = 0, se = 0;
    for (int q = t; q < 32768; q += 256) {
        int b = q >> 9, d = q & 511;
        float v = A[(size_t)b * 13824 + (i << 9) + d];
        float e = eE[q];
        s += v; s2 = fmaf(v, v, s2); se = fmaf(v, e, se);
    }
    for (int off = 32; off > 0; off >>= 1) {
        s += __shfl_down(s, off); s2 += __shfl_down(s2, off); se += __shfl_down(se, off);
    }
    __shared__ float p[3][4];
    int wid = t >> 6, lane = t & 63;
    if (lane == 0) { p[0][wid] = s; p[1][wid] = s2; p[2][wid] = se; }
    __syncthreads();
    if (t == 0) {
        o[i]      = p[0][0] + p[0][1] + p[0][2] + p[0][3];
        o[27 + i] = p[1][0] + p[1][1] + p[1][2] + p[1][3];
        o[54 + i] = p[2][0] + p[2][1] + p[2][2] + p[2][3];
    }
}

// ---------- Se, Se2 ----------
__global__ __launch_bounds__(256) void e_sums_k(const float* __restrict__ eE, float* __restrict__ o) {
    int t = threadIdx.x;
    float s = 0, s2 = 0;
    for (int q = t; q < 32768; q += 256) { float v = eE[q]; s += v; s2 = fmaf(v, v, s2); }
    for (int off = 32; off > 0; off >>= 1) { s += __shfl_down(s, off); s2 += __shfl_down(s2, off); }
    __shared__ float p[2][4];
    int wid = t >> 6, lane = t & 63;
    if (lane == 0) { p[0][wid] = s; p[1][wid] = s2; }
    __syncthreads();
    if (t == 0) {
        o[0] = p[0][0] + p[0][1] + p[0][2] + p[0][3];
        o[1] = p[1][0] + p[1][1] + p[1][2] + p[1][3];
    }
}

// ---------- Gram partials: pac[zb][i*27+j] = sum over (b fixed, 128 d's) a*c ----------
__global__ __launch_bounds__(256) void gram_partial_k(const float* __restrict__ a, const float* __restrict__ c,
                                                      float* __restrict__ pac) {
    __shared__ float As[27][136];
    __shared__ float Cs[27][136];
    int b = blockIdx.x, dc = blockIdx.y;
    int t = threadIdx.x;
    const float* abase = a + (size_t)b * 13824 + dc * 128;
    const float* cbase = c + (size_t)b * 13824 + dc * 128;
    for (int q4 = t; q4 < 864; q4 += 256) {
        int row = q4 >> 5, col = (q4 & 31) << 2;
        float4 av = *(const float4*)(abase + row * 512 + col);
        float4 cv = *(const float4*)(cbase + row * 512 + col);
        *(float4*)&As[row][col] = av;
        *(float4*)&Cs[row][col] = cv;
    }
    __syncthreads();
    if (t < 243) {
        int i = t / 9, j0 = (t % 9) * 3;
        float a0 = 0, a1 = 0, a2 = 0;
#pragma unroll
        for (int k = 0; k < 128; k += 4) {
            float4 av = *(const float4*)&As[i][k];
            float4 c0 = *(const float4*)&Cs[j0][k];
            float4 c1 = *(const float4*)&Cs[j0 + 1][k];
            float4 c2 = *(const float4*)&Cs[j0 + 2][k];
            a0 += av.x * c0.x + av.y * c0.y + av.z * c0.z + av.w * c0.w;
            a1 += av.x * c1.x + av.y * c1.y + av.z * c1.z + av.w * c1.w;
            a2 += av.x * c2.x + av.y * c2.y + av.z * c2.z + av.w * c2.w;
        }
        int zb = dc * 64 + b;
        float* prow = pac + (size_t)zb * 729 + i * 27 + j0;
        prow[0] = a0; prow[1] = a1; prow[2] = a2;
    }
}

// ---------- finalize msg BN stats: mtab[p], rstab[p] (p = i*27+j) ----------
__global__ __launch_bounds__(256) void gram_finalize_k(const float* __restrict__ pac, const float* __restrict__ stats,
                                                       float* __restrict__ mtab, float* __restrict__ rstab) {
    int p = blockIdx.x * 256 + threadIdx.x;
    if (p >= 729) return;
    float sac = 0;
    for (int zb = 0; zb < 256; zb++) sac += pac[(size_t)zb * 729 + p];
    int i = p / 27, j = p % 27;
    float Sa = stats[i], Sa2 = stats[27 + i], Sae = stats[54 + i];
    float Sc = stats[81 + j], Sc2 = stats[108 + j], Sce = stats[135 + j];
    float Se = stats[162], Se2 = stats[163];
    const float inv = 1.f / 32768.f;
    float m = (Sa + Sc + Se) * inv;
    float S2 = Sa2 + Sc2 + Se2 + 2.f * (sac + Sae + Sce);
    float var = S2 * inv - m * m;
    mtab[p] = m;
    rstab[p] = 1.f / sqrtf(var + EPSC);
}

// ---------- fused gate/softmax/aggregate: xn[b,i,d] ----------
__global__ __launch_bounds__(256) void fuse_agg_k(const float* __restrict__ a, const float* __restrict__ c,
        const float* __restrict__ u, const float* __restrict__ w,
        const float* __restrict__ eE, const float* __restrict__ eN,
        const float* __restrict__ mtab, const float* __restrict__ rstab,
        float* __restrict__ xn) {
    __shared__ float ms[9][27], rss[9][27];
    int t = threadIdx.x;
    int i0 = blockIdx.y * 9;
    if (t < 243) {
        int ii = t / 27, jj = t % 27;
        ms[ii][jj] = mtab[(i0 + ii) * 27 + jj];
        rss[ii][jj] = rstab[(i0 + ii) * 27 + jj];
    }
    __syncthreads();
    int q = blockIdx.x * 256 + t;
    int b = q >> 9, d = q & 511;
    size_t rb = (size_t)b * 13824 + d;
    float cr[27], ur[27];
#pragma unroll
    for (int j = 0; j < 27; j++) { cr[j] = c[rb + (j << 9)]; ur[j] = u[rb + (j << 9)]; }
    float ev = eE[q], env = eN[q];
    for (int ii = 0; ii < 9; ii++) {
        int i = i0 + ii;
        float t1 = a[rb + (i << 9)] + ev;
        float num = 0, den = 0;
#pragma unroll
        for (int j = 0; j < 27; j++) {
            float bn = (t1 + cr[j] - ms[ii][j]) * rss[ii][j];
            float r = fmaxf(bn, 0.f);
            float z = env + r;
            float sg = 1.f / (1.f + __expf(-z));
            float wj = __expf(sg);
            den += wj;
            num = fmaf(wj, ur[j], num);
        }
        xn[rb + (i << 9)] = w[rb + (i << 9)] + num / (den * 27.f);
    }
}

// ---------- per-n BN stats of xn ----------
__global__ __launch_bounds__(256) void bn_per_n_k(const float* __restrict__ xn, float* __restrict__ m2,
                                                  float* __restrict__ rs2) {
    int n = blockIdx.x, t = threadIdx.x;
    float s = 0, s2 = 0;
    for (int q = t; q < 32768; q += 256) {
        int b = q >> 9, d = q & 511;
        float v = xn[(size_t)b * 13824 + (n << 9) + d];
        s += v; s2 = fmaf(v, v, s2);
    }
    for (int off = 32; off > 0; off >>= 1) { s += __shfl_down(s, off); s2 += __shfl_down(s2, off); }
    __shared__ float p[2][4];
    int wid = t >> 6, lane = t & 63;
    if (lane == 0) { p[0][wid] = s; p[1][wid] = s2; }
    __syncthreads();
    if (t == 0) {
        float S = p[0][0] + p[0][1] + p[0][2] + p[0][3];
        float S2 = p[1][0] + p[1][1] + p[1][2] + p[1][3];
        float m = S * (1.f / 32768.f);
        float var = S2 * (1.f / 32768.f) - m * m;
        m2[n] = m;
        rs2[n] = 1.f / sqrtf(var + EPSC);
    }
}

// ---------- out = relu(x + (xn - m2[n]) * rs2[n]) ----------
__global__ __launch_bounds__(256) void final_k(const float* __restrict__ x, const float* __restrict__ xn,
        const float* __restrict__ m2, const float* __restrict__ rs2, float* __restrict__ out) {
    int q4 = blockIdx.x * 256 + threadIdx.x;   // 0..221183
    int flat = q4 << 2;
    int n = (flat >> 9) % 27;
    float m = m2[n], rs = rs2[n];
    float4 xv = ((const float4*)x)[q4];
    float4 xnv = ((const float4*)xn)[q4];
    float4 o;
    o.x = fmaxf(fmaf(xnv.x - m, rs, xv.x), 0.f);
    o.y = fmaxf(fmaf(xnv.y - m, rs, xv.y), 0.f);
    o.z = fmaxf(fmaf(xnv.z - m, rs, xv.z), 0.f);
    o.w = fmaxf(fmaf(xnv.w - m, rs, xv.w), 0.f);
    ((float4*)out)[q4] = o;
}

extern "C" void kernel_launch(void* const* d_in, const int* in_sizes, int n_in,
                              void* d_out, int out_size, void* d_ws, size_t ws_size,
                              hipStream_t stream) {
    const float* x    = (const float*)d_in[0];
    const float* gl_w = (const float*)d_in[1];
    const float* gl_b = (const float*)d_in[2];
    // fq/fk (3..6) and aq/ak (9..12) are mathematically irrelevant (uniform softmax)
    const float* fv_w = (const float*)d_in[7];
    const float* fv_b = (const float*)d_in[8];
    const float* av_w = (const float*)d_in[13];
    const float* av_b = (const float*)d_in[14];
    const float* ep_w = (const float*)d_in[15];
    const float* ep_b = (const float*)d_in[16];
    const float* U1   = (const float*)d_in[17];
    const float* V1   = (const float*)d_in[18];
    const float* A1   = (const float*)d_in[19];
    const float* B1   = (const float*)d_in[20];
    const float* E1   = (const float*)d_in[21];
    float* out = (float*)d_out;
    float* ws = (float*)d_ws;   // needs ~19.5 MB

    float* gf    = ws;            // 32768
    float* g0    = ws + 32768;
    float* g     = ws + 65536;
    float* fvg   = ws + 98304;
    float* h     = ws + 131072;
    float* e0    = ws + 163840;
    float* eN    = ws + 196608;
    float* eE    = ws + 229376;
    float* a     = ws + 262144;   // A1x (B,N,D)
    float* c     = ws + 1146880;  // B1x
    float* u     = ws + 2031616;  // V1x
    float* w     = ws + 2916352;  // U1x
    float* xn    = ws + 3801088;
    float* pac   = ws + 4685824;  // 256*729
    float* stats = ws + 4872448;  // 218 floats
    float* mtab  = ws + 4872704;  // 729
    float* rstab = ws + 4873433;  // 729
    float* m2    = stats + 164;
    float* rs2   = stats + 191;

    colmean_k<<<128, 256, 0, stream>>>(x, gf);
    small_gemm_k<<<128, 256, 0, stream>>>(gf, gl_w, gl_b, g0);
    bn_batch_relu_k<<<2, 256, 0, stream>>>(g0, g);
    small_gemm_k<<<128, 256, 0, stream>>>(g, fv_w, fv_b, fvg);
    small_gemm_k<<<128, 256, 0, stream>>>(fvg, av_w, av_b, h);
    small_gemm_k<<<128, 256, 0, stream>>>(h, ep_w, ep_b, e0);
    scalar_bn_k<<<1, 1024, 0, stream>>>(e0, eN);
    small_gemm_k<<<128, 256, 0, stream>>>(eN, E1, nullptr, eE);

    gemm4_k<<<dim3(27, 8, 4), 256, 0, stream>>>(x, A1, B1, V1, U1, a, c, u, w);

    row_sums_k<<<27, 256, 0, stream>>>(a, eE, stats);        // Sa, Sa2, Sae
    row_sums_k<<<27, 256, 0, stream>>>(c, eE, stats + 81);   // Sc, Sc2, Sce
    e_sums_k<<<1, 256, 0, stream>>>(eE, stats + 162);        // Se, Se2
    gram_partial_k<<<dim3(64, 4), 256, 0, stream>>>(a, c, pac);
    gram_finalize_k<<<3, 256, 0, stream>>>(pac, stats, mtab, rstab);

    fuse_agg_k<<<dim3(128, 3), 256, 0, stream>>>(a, c, u, w, eE, eN, mtab, rstab, xn);
    bn_per_n_k<<<27, 256, 0, stream>>>(xn, m2, rs2);
    final_k<<<864, 256, 0, stream>>>(x, xn, m2, rs2, out);
}

// Round 2
// 263.390 us; speedup vs baseline: 1.2814x; 1.2814x over previous
//
#include <hip/hip_runtime.h>
#include <math.h>

// B=64, N=27, D=512. EPS=1e-5.
// Identity: both cross-attns have K/V constant along key axis -> uniform
// softmax -> output == the V row. All N^2 tensors are broadcasts of (B,D)
// vectors; msg BN stats decompose into per-i/per-j sums + a 27x27 Gram.
// Big GEMM (x @ {A1,B1,V1,U1}^T, M=1728,K=512,N=2048) done in bf16 MFMA.

#define EPSC 1e-5f

typedef short short8 __attribute__((ext_vector_type(8)));
typedef float f32x4 __attribute__((ext_vector_type(4)));

__device__ __forceinline__ unsigned short f2bf(float f) {
    unsigned int u = __float_as_uint(f);
    return (unsigned short)((u + 0x7FFFu + ((u >> 16) & 1u)) >> 16);
}

// ---------- bf16 MFMA GEMM: Y[r, wi*512+d] = sum_k X[r,k] * Wwi[d,k] ----------
// M=1728 (pad 1792), N=2048, K=512. BM=BN=128, BK=32. 256 thr = 4 waves (2x2).
__global__ __launch_bounds__(256) void mfma_gemm_k(const float* __restrict__ X,
        const float* __restrict__ W0, const float* __restrict__ W1,
        const float* __restrict__ W2, const float* __restrict__ W3,
        float* __restrict__ Y) {
    __shared__ __align__(16) unsigned short As[128 * 32];
    __shared__ __align__(16) unsigned short Bs[128 * 32];
    int t = threadIdx.x;
    int rb0 = blockIdx.x * 128;
    int n0 = blockIdx.y * 128;
    const float* Wsel;
    switch (blockIdx.y >> 2) {
        case 0: Wsel = W0; break; case 1: Wsel = W1; break;
        case 2: Wsel = W2; break; default: Wsel = W3; break;
    }
    int wrow0 = (blockIdx.y & 3) * 128;

    // staging role: t<128 -> A rows, t>=128 -> B rows; lane->row remap keeps
    // ds_write_b128 at the 2-per-bank-quad floor.
    int tt = t & 127;
    int sr = (tt & 64) + (((tt & 1) << 5) | ((tt & 63) >> 1));
    bool isB = t >= 128;
    const float* src;
    bool valid;
    if (!isB) { int gr = rb0 + sr; valid = gr < 1728; src = X + (size_t)gr * 512; }
    else      { valid = true;      src = Wsel + (size_t)(wrow0 + sr) * 512; }
    unsigned short* dst = (isB ? Bs : As) + sr * 32;
    int rsh = (sr >> 1) & 3;

    int wave = t >> 6, l = t & 63;
    int wr = (wave >> 1) * 64, wc = (wave & 1) * 64;
    int lr = l & 15, g = l >> 4;

    f32x4 acc[4][4] = {};
    float4 v[8];
    float4 z4 = make_float4(0.f, 0.f, 0.f, 0.f);
#pragma unroll
    for (int i = 0; i < 8; i++) v[i] = valid ? ((const float4*)src)[i] : z4;

    for (int step = 0; step < 16; step++) {
        __syncthreads();
#pragma unroll
        for (int s = 0; s < 4; s++) {
            uint4 pk;
            pk.x = f2bf(v[2 * s].x) | ((unsigned)f2bf(v[2 * s].y) << 16);
            pk.y = f2bf(v[2 * s].z) | ((unsigned)f2bf(v[2 * s].w) << 16);
            pk.z = f2bf(v[2 * s + 1].x) | ((unsigned)f2bf(v[2 * s + 1].y) << 16);
            pk.w = f2bf(v[2 * s + 1].z) | ((unsigned)f2bf(v[2 * s + 1].w) << 16);
            *(uint4*)(dst + (((s + rsh) & 3) << 3)) = pk;
        }
        __syncthreads();
        if (step < 15) {
            const float4* nsrc = (const float4*)(src + (step + 1) * 32);
#pragma unroll
            for (int i = 0; i < 8; i++) v[i] = valid ? nsrc[i] : z4;
        }
        short8 af[4], bf[4];
#pragma unroll
        for (int m = 0; m < 4; m++) {
            int r = wr + m * 16 + lr;
            af[m] = *(const short8*)(As + r * 32 + (((g + (r >> 1)) & 3) << 3));
        }
#pragma unroll
        for (int n = 0; n < 4; n++) {
            int r = wc + n * 16 + lr;
            bf[n] = *(const short8*)(Bs + r * 32 + (((g + (r >> 1)) & 3) << 3));
        }
#pragma unroll
        for (int m = 0; m < 4; m++)
#pragma unroll
            for (int n = 0; n < 4; n++)
                acc[m][n] = __builtin_amdgcn_mfma_f32_16x16x32_bf16(af[m], bf[n], acc[m][n], 0, 0, 0);
    }
    // C layout: col = lane&15, row = (lane>>4)*4 + reg
#pragma unroll
    for (int m = 0; m < 4; m++) {
        int row0 = rb0 + wr + m * 16 + g * 4;
#pragma unroll
        for (int reg = 0; reg < 4; reg++) {
            int row = row0 + reg;
            if (row < 1728) {
#pragma unroll
                for (int n = 0; n < 4; n++)
                    Y[(size_t)row * 2048 + n0 + wc + n * 16 + lr] = acc[m][n][reg];
            }
        }
    }
}

// ---------- gf[b,d] = mean_n x[b,n,d] ----------
__global__ __launch_bounds__(256) void colmean_k(const float* __restrict__ x, float* __restrict__ gf) {
    int q = blockIdx.x * 256 + threadIdx.x;
    int b = q >> 9, d = q & 511;
    const float* p = x + (size_t)b * 13824 + d;
    float s = 0.f;
#pragma unroll
    for (int n = 0; n < 27; n++) s += p[n << 9];
    gf[q] = s * (1.0f / 27.0f);
}

// ---------- small GEMM: Y[b,d] = sum_k X[b,k] W[d,k] (+bias), B=64,D=K=512 ----------
__global__ __launch_bounds__(256) void small_gemm_k(const float* __restrict__ X, const float* __restrict__ W,
                                                    const float* __restrict__ bias, float* __restrict__ Y) {
    __shared__ float xs[512];
    int t = threadIdx.x;
    int b = blockIdx.x >> 1;
    int d = ((blockIdx.x & 1) << 8) + t;
    xs[t] = X[(b << 9) + t];
    xs[t + 256] = X[(b << 9) + t + 256];
    __syncthreads();
    const float4* wr = (const float4*)(W + (size_t)d * 512);
    const float4* xr = (const float4*)xs;
    float a0 = 0, a1 = 0, a2 = 0, a3 = 0;
#pragma unroll 8
    for (int k = 0; k < 128; k++) {
        float4 xv = xr[k]; float4 wv = wr[k];
        a0 = fmaf(xv.x, wv.x, a0); a1 = fmaf(xv.y, wv.y, a1);
        a2 = fmaf(xv.z, wv.z, a2); a3 = fmaf(xv.w, wv.w, a3);
    }
    float r = (a0 + a1) + (a2 + a3);
    if (bias) r += bias[d];
    Y[(b << 9) + d] = r;
}

// ---------- BN over batch + ReLU ----------
__global__ __launch_bounds__(256) void bn_batch_relu_k(const float* __restrict__ g0, float* __restrict__ g) {
    int d = blockIdx.x * 256 + threadIdx.x;
    float s = 0, s2 = 0;
    for (int b = 0; b < 64; b++) { float v = g0[(b << 9) + d]; s += v; s2 = fmaf(v, v, s2); }
    float m = s * (1.f / 64.f);
    float var = s2 * (1.f / 64.f) - m * m;
    float rs = 1.f / sqrtf(var + EPSC);
    for (int b = 0; b < 64; b++) {
        float v = (g0[(b << 9) + d] - m) * rs;
        g[(b << 9) + d] = fmaxf(v, 0.f);
    }
}

// ---------- scalar BN over all (b,d) ----------
__global__ __launch_bounds__(1024) void scalar_bn_k(const float* __restrict__ e0, float* __restrict__ eN) {
    int t = threadIdx.x;
    float s = 0, s2 = 0;
    for (int q = t; q < 32768; q += 1024) { float v = e0[q]; s += v; s2 = fmaf(v, v, s2); }
    for (int off = 32; off > 0; off >>= 1) { s += __shfl_down(s, off); s2 += __shfl_down(s2, off); }
    __shared__ float p1[16], p2[16];
    __shared__ float mb[2];
    int wid = t >> 6, lane = t & 63;
    if (lane == 0) { p1[wid] = s; p2[wid] = s2; }
    __syncthreads();
    if (t == 0) {
        float S = 0, S2 = 0;
        for (int w = 0; w < 16; w++) { S += p1[w]; S2 += p2[w]; }
        float m = S * (1.f / 32768.f);
        float var = S2 * (1.f / 32768.f) - m * m;
        mb[0] = m; mb[1] = 1.f / sqrtf(var + EPSC);
    }
    __syncthreads();
    float m = mb[0], rs = mb[1];
    for (int q = t; q < 32768; q += 1024) eN[q] = (e0[q] - m) * rs;
}

// ---------- merged stats: blocks 0-26 -> a-row i, 27-53 -> c-row i, 54 -> eE ----------
__global__ __launch_bounds__(256) void stats_k(const float* __restrict__ Y, const float* __restrict__ eE,
                                               float* __restrict__ o) {
    int blk = blockIdx.x, t = threadIdx.x;
    float s = 0, s2 = 0, se = 0;
    if (blk < 54) {
        int i = (blk < 27) ? blk : blk - 27;
        const float* P = Y + (blk < 27 ? 0 : 512);
        for (int q = t; q < 32768; q += 256) {
            int b = q >> 9, d = q & 511;
            float v = P[(size_t)(b * 27 + i) * 2048 + d];
            float e = eE[q];
            s += v; s2 = fmaf(v, v, s2); se = fmaf(v, e, se);
        }
    } else {
        for (int q = t; q < 32768; q += 256) { float v = eE[q]; s += v; s2 = fmaf(v, v, s2); }
    }
    for (int off = 32; off > 0; off >>= 1) {
        s += __shfl_down(s, off); s2 += __shfl_down(s2, off); se += __shfl_down(se, off);
    }
    __shared__ float p[3][4];
    int wid = t >> 6, lane = t & 63;
    if (lane == 0) { p[0][wid] = s; p[1][wid] = s2; p[2][wid] = se; }
    __syncthreads();
    if (t == 0) {
        float S = p[0][0] + p[0][1] + p[0][2] + p[0][3];
        float S2 = p[1][0] + p[1][1] + p[1][2] + p[1][3];
        float Se = p[2][0] + p[2][1] + p[2][2] + p[2][3];
        if (blk < 27)      { o[blk] = S; o[27 + blk] = S2; o[54 + blk] = Se; }
        else if (blk < 54) { int i = blk - 27; o[81 + i] = S; o[108 + i] = S2; o[135 + i] = Se; }
        else               { o[162] = S; o[163] = S2; }
    }
}

// ---------- Gram partials per b: pac[b][i*27+j] = sum_d a[b,i,d] c[b,j,d] ----------
__global__ __launch_bounds__(256) void gram_partial_k(const float* __restrict__ Y, float* __restrict__ pac) {
    __shared__ float As[27][132];
    __shared__ float Cs[27][132];
    int b = blockIdx.x, t = threadIdx.x;
    float a0 = 0, a1 = 0, a2 = 0;
    int i = t / 9, j0 = (t % 9) * 3;
    for (int dc = 0; dc < 4; dc++) {
        const float* base = Y + (size_t)b * 27 * 2048 + dc * 128;
        for (int q4 = t; q4 < 864; q4 += 256) {
            int row = q4 >> 5, col = (q4 & 31) << 2;
            float4 av = *(const float4*)(base + (size_t)row * 2048 + col);
            float4 cv = *(const float4*)(base + (size_t)row * 2048 + 512 + col);
            *(float4*)&As[row][col] = av;
            *(float4*)&Cs[row][col] = cv;
        }
        __syncthreads();
        if (t < 243) {
#pragma unroll
            for (int k = 0; k < 128; k += 4) {
                float4 av = *(const float4*)&As[i][k];
                float4 c0 = *(const float4*)&Cs[j0][k];
                float4 c1 = *(const float4*)&Cs[j0 + 1][k];
                float4 c2 = *(const float4*)&Cs[j0 + 2][k];
                a0 += av.x * c0.x + av.y * c0.y + av.z * c0.z + av.w * c0.w;
                a1 += av.x * c1.x + av.y * c1.y + av.z * c1.z + av.w * c1.w;
                a2 += av.x * c2.x + av.y * c2.y + av.z * c2.z + av.w * c2.w;
            }
        }
        __syncthreads();
    }
    if (t < 243) {
        float* prow = pac + (size_t)b * 729 + i * 27 + j0;
        prow[0] = a0; prow[1] = a1; prow[2] = a2;
    }
}

// ---------- finalize msg BN stats ----------
__global__ __launch_bounds__(256) void gram_finalize_k(const float* __restrict__ pac, const float* __restrict__ stats,
                                                       float* __restrict__ mtab, float* __restrict__ rstab) {
    int p = blockIdx.x * 256 + threadIdx.x;
    if (p >= 729) return;
    float sac = 0;
    for (int zb = 0; zb < 64; zb++) sac += pac[(size_t)zb * 729 + p];
    int i = p / 27, j = p % 27;
    float Sa = stats[i], Sa2 = stats[27 + i], Sae = stats[54 + i];
    float Sc = stats[81 + j], Sc2 = stats[108 + j], Sce = stats[135 + j];
    float Se = stats[162], Se2 = stats[163];
    const float inv = 1.f / 32768.f;
    float m = (Sa + Sc + Se) * inv;
    float S2 = Sa2 + Sc2 + Se2 + 2.f * (sac + Sae + Sce);
    float var = S2 * inv - m * m;
    mtab[p] = m;
    rstab[p] = 1.f / sqrtf(var + EPSC);
}

// ---------- fused gate/softmax/aggregate: xn[b,i,d] ----------
__global__ __launch_bounds__(256) void fuse_agg_k(const float* __restrict__ Yb,
        const float* __restrict__ eE, const float* __restrict__ eN,
        const float* __restrict__ mtab, const float* __restrict__ rstab,
        float* __restrict__ xn) {
    __shared__ float ms[9][27], rss[9][27];
    int t = threadIdx.x;
    int i0 = blockIdx.y * 9;
    if (t < 243) {
        int ii = t / 27, jj = t % 27;
        ms[ii][jj] = mtab[(i0 + ii) * 27 + jj];
        rss[ii][jj] = rstab[(i0 + ii) * 27 + jj];
    }
    __syncthreads();
    int q = blockIdx.x * 256 + t;
    int b = q >> 9, d = q & 511;
    size_t base = (size_t)b * 27 * 2048 + d;
    float cr[27], ur[27];
#pragma unroll
    for (int j = 0; j < 27; j++) {
        cr[j] = Yb[base + (size_t)j * 2048 + 512];
        ur[j] = Yb[base + (size_t)j * 2048 + 1024];
    }
    float ev = eE[q], env = eN[q];
    size_t xb = (size_t)b * 13824 + d;
    for (int ii = 0; ii < 9; ii++) {
        int i = i0 + ii;
        float t1 = Yb[base + (size_t)i * 2048] + ev;
        float num = 0, den = 0;
#pragma unroll
        for (int j = 0; j < 27; j++) {
            float bn = (t1 + cr[j] - ms[ii][j]) * rss[ii][j];
            float r = fmaxf(bn, 0.f);
            float z = env + r;
            float sg = 1.f / (1.f + __expf(-z));
            float wj = __expf(sg);
            den += wj;
            num = fmaf(wj, ur[j], num);
        }
        xn[xb + (i << 9)] = Yb[base + (size_t)i * 2048 + 1536] + num / (den * 27.f);
    }
}

// ---------- per-n BN stats of xn ----------
__global__ __launch_bounds__(256) void bn_per_n_k(const float* __restrict__ xn, float* __restrict__ m2,
                                                  float* __restrict__ rs2) {
    int n = blockIdx.x, t = threadIdx.x;
    float s = 0, s2 = 0;
    for (int q = t; q < 32768; q += 256) {
        int b = q >> 9, d = q & 511;
        float v = xn[(size_t)b * 13824 + (n << 9) + d];
        s += v; s2 = fmaf(v, v, s2);
    }
    for (int off = 32; off > 0; off >>= 1) { s += __shfl_down(s, off); s2 += __shfl_down(s2, off); }
    __shared__ float p[2][4];
    int wid = t >> 6, lane = t & 63;
    if (lane == 0) { p[0][wid] = s; p[1][wid] = s2; }
    __syncthreads();
    if (t == 0) {
        float S = p[0][0] + p[0][1] + p[0][2] + p[0][3];
        float S2 = p[1][0] + p[1][1] + p[1][2] + p[1][3];
        float m = S * (1.f / 32768.f);
        float var = S2 * (1.f / 32768.f) - m * m;
        m2[n] = m;
        rs2[n] = 1.f / sqrtf(var + EPSC);
    }
}

// ---------- out = relu(x + (xn - m2[n]) * rs2[n]) ----------
__global__ __launch_bounds__(256) void final_k(const float* __restrict__ x, const float* __restrict__ xn,
        const float* __restrict__ m2, const float* __restrict__ rs2, float* __restrict__ out) {
    int q4 = blockIdx.x * 256 + threadIdx.x;
    int flat = q4 << 2;
    int n = (flat >> 9) % 27;
    float m = m2[n], rs = rs2[n];
    float4 xv = ((const float4*)x)[q4];
    float4 xnv = ((const float4*)xn)[q4];
    float4 o;
    o.x = fmaxf(fmaf(xnv.x - m, rs, xv.x), 0.f);
    o.y = fmaxf(fmaf(xnv.y - m, rs, xv.y), 0.f);
    o.z = fmaxf(fmaf(xnv.z - m, rs, xv.z), 0.f);
    o.w = fmaxf(fmaf(xnv.w - m, rs, xv.w), 0.f);
    ((float4*)out)[q4] = o;
}

extern "C" void kernel_launch(void* const* d_in, const int* in_sizes, int n_in,
                              void* d_out, int out_size, void* d_ws, size_t ws_size,
                              hipStream_t stream) {
    const float* x    = (const float*)d_in[0];
    const float* gl_w = (const float*)d_in[1];
    const float* gl_b = (const float*)d_in[2];
    const float* fv_w = (const float*)d_in[7];
    const float* fv_b = (const float*)d_in[8];
    const float* av_w = (const float*)d_in[13];
    const float* av_b = (const float*)d_in[14];
    const float* ep_w = (const float*)d_in[15];
    const float* ep_b = (const float*)d_in[16];
    const float* U1   = (const float*)d_in[17];
    const float* V1   = (const float*)d_in[18];
    const float* A1   = (const float*)d_in[19];
    const float* B1   = (const float*)d_in[20];
    const float* E1   = (const float*)d_in[21];
    float* out = (float*)d_out;
    float* ws = (float*)d_ws;

    // Y layout: row r = b*27+i, cols [0:512)=a (A1x), [512:1024)=c (B1x),
    //           [1024:1536)=u (V1x), [1536:2048)=w (U1x)
    float* Yb    = ws;                 // 1728*2048 = 3,538,944
    float* gf    = ws + 3538944;
    float* g0    = gf + 32768;
    float* g     = g0 + 32768;
    float* fvg   = g  + 32768;
    float* h     = fvg + 32768;
    float* e0    = h  + 32768;
    float* eN    = e0 + 32768;
    float* eE    = eN + 32768;
    float* xn    = ws + 3801088;       // 884,736
    float* pac   = ws + 4685824;       // 64*729 = 46,656
    float* stats = ws + 4732480;       // 256
    float* mtab  = ws + 4732736;       // 729
    float* rstab = ws + 4733465;       // 729  (total ~18.94 MB)
    float* m2    = stats + 164;
    float* rs2   = stats + 191;

    mfma_gemm_k<<<dim3(14, 16), 256, 0, stream>>>(x, A1, B1, V1, U1, Yb);

    colmean_k<<<128, 256, 0, stream>>>(x, gf);
    small_gemm_k<<<128, 256, 0, stream>>>(gf, gl_w, gl_b, g0);
    bn_batch_relu_k<<<2, 256, 0, stream>>>(g0, g);
    small_gemm_k<<<128, 256, 0, stream>>>(g, fv_w, fv_b, fvg);
    small_gemm_k<<<128, 256, 0, stream>>>(fvg, av_w, av_b, h);
    small_gemm_k<<<128, 256, 0, stream>>>(h, ep_w, ep_b, e0);
    scalar_bn_k<<<1, 1024, 0, stream>>>(e0, eN);
    small_gemm_k<<<128, 256, 0, stream>>>(eN, E1, nullptr, eE);

    stats_k<<<55, 256, 0, stream>>>(Yb, eE, stats);
    gram_partial_k<<<64, 256, 0, stream>>>(Yb, pac);
    gram_finalize_k<<<3, 256, 0, stream>>>(pac, stats, mtab, rstab);

    fuse_agg_k<<<dim3(128, 3), 256, 0, stream>>>(Yb, eE, eN, mtab, rstab, xn);
    bn_per_n_k<<<27, 256, 0, stream>>>(xn, m2, rs2);
    final_k<<<864, 256, 0, stream>>>(x, xn, m2, rs2, out);
}